// Round 3
// baseline (163.794 us; speedup 1.0000x reference)
//
#include <hip/hip_runtime.h>
#include <hip/hip_bf16.h>
#include <math.h>

// Problem constants
#define Bc 4
#define Nc 1024
#define Ec 1024
#define Hc 16
#define Dc 64
#define Mc 4096              // B*N rows
#define OUT0_ELEMS 4194304   // B*H*N*D

typedef __attribute__((ext_vector_type(4))) float f32x4;
typedef __attribute__((ext_vector_type(16))) float f32x16;
typedef __attribute__((ext_vector_type(8))) short s16x8;
typedef __attribute__((ext_vector_type(4))) short s16x4;

// Hardware bf16 convert: compiler pairs these into v_cvt_pk_bf16_f32.
__device__ __forceinline__ short f2bf(float f) {
    union { __bf16 h; short s; } c;
    c.h = (__bf16)f;
    return c.s;
}
__device__ __forceinline__ s16x4 pk4(const f32x4 v) {
    s16x4 r;
    r[0] = f2bf(v[0]); r[1] = f2bf(v[1]); r[2] = f2bf(v[2]); r[3] = f2bf(v[3]);
    return r;
}

// ---------------------------------------------------------------------------
// Projection GEMM (UNCHANGED from round 2): out = X @ W^T + b.
// sel 0 -> Q (bf16 ws), 1 -> K (bf16 ws), 2 -> V (fp32 to d_out).
// 128x128 tile, BK=64, 4 waves (2x2 of 64x64), reg-prefetch pipeline.
// ---------------------------------------------------------------------------
__global__ __launch_bounds__(256, 2)
void proj_kernel(const float* __restrict__ q, const float* __restrict__ k,
                 const float* __restrict__ v, const float* __restrict__ Wq,
                 const float* __restrict__ Wk, const float* __restrict__ Wv,
                 const float* __restrict__ bq, const float* __restrict__ bk,
                 const float* __restrict__ bv,
                 short* __restrict__ qws, short* __restrict__ kws,
                 float* __restrict__ vout)
{
    const int sel = blockIdx.z;
    const float* X    = (sel == 0) ? q  : (sel == 1) ? k  : v;
    const float* W    = (sel == 0) ? Wq : (sel == 1) ? Wk : Wv;
    const float* bias = (sel == 0) ? bq : (sel == 1) ? bk : bv;

    __shared__ __align__(16) short lA[128 * 72];
    __shared__ __align__(16) short lB[128 * 72];

    const int t    = threadIdx.x;
    const int lane = t & 63;
    const int w    = t >> 6;
    const int wr   = w >> 1, wc = w & 1;
    const int li   = lane & 15, g = lane >> 4;
    const int bm   = blockIdx.x * 128;
    const int bn   = blockIdx.y * 128;

    const int srow = t >> 4;
    const int scol = (t & 15) * 4;

    const float* Xb = X + (size_t)bm * Ec;
    const float* Wb = W + (size_t)bn * Ec;

    f32x4 rA[8], rB[8];
#pragma unroll
    for (int j = 0; j < 8; ++j) {
        const int r = j * 16 + srow;
        rA[j] = *(const f32x4*)(Xb + (size_t)r * Ec + scol);
        rB[j] = *(const f32x4*)(Wb + (size_t)r * Ec + scol);
    }

    f32x4 acc[4][4];
#pragma unroll
    for (int i = 0; i < 4; ++i)
#pragma unroll
        for (int j = 0; j < 4; ++j)
            acc[i][j] = (f32x4){0.f, 0.f, 0.f, 0.f};

    for (int kt = 0; kt < 16; ++kt) {
#pragma unroll
        for (int j = 0; j < 8; ++j) {
            const int r = j * 16 + srow;
            *(s16x4*)&lA[r * 72 + scol] = pk4(rA[j]);
            *(s16x4*)&lB[r * 72 + scol] = pk4(rB[j]);
        }
        __syncthreads();

        if (kt < 15) {
            const int kb = (kt + 1) * 64;
#pragma unroll
            for (int j = 0; j < 8; ++j) {
                const int r = j * 16 + srow;
                rA[j] = *(const f32x4*)(Xb + (size_t)r * Ec + kb + scol);
                rB[j] = *(const f32x4*)(Wb + (size_t)r * Ec + kb + scol);
            }
        }

#pragma unroll
        for (int s = 0; s < 2; ++s) {
            s16x8 aF[4], bF[4];
#pragma unroll
            for (int mt = 0; mt < 4; ++mt)
                aF[mt] = *(const s16x8*)&lA[(wr * 64 + mt * 16 + li) * 72 + s * 32 + g * 8];
#pragma unroll
            for (int nt = 0; nt < 4; ++nt)
                bF[nt] = *(const s16x8*)&lB[(wc * 64 + nt * 16 + li) * 72 + s * 32 + g * 8];
#pragma unroll
            for (int mt = 0; mt < 4; ++mt)
#pragma unroll
                for (int nt = 0; nt < 4; ++nt)
                    acc[mt][nt] = __builtin_amdgcn_mfma_f32_16x16x32_bf16(
                        aF[mt], bF[nt], acc[mt][nt], 0, 0, 0);
        }
        __syncthreads();
    }

    short* dstBF = (sel == 0) ? qws : kws;
#pragma unroll
    for (int nt = 0; nt < 4; ++nt) {
        const int col = bn + wc * 64 + nt * 16 + li;
        const float bcol = bias[col];
        const int h = col >> 6, d = col & 63;
#pragma unroll
        for (int mt = 0; mt < 4; ++mt) {
#pragma unroll
            for (int r = 0; r < 4; ++r) {
                const int row = bm + wr * 64 + mt * 16 + g * 4 + r;
                const int bb = row >> 10, n = row & 1023;
                const size_t off =
                    ((size_t)(bb * Hc + h) * Nc + n) * Dc + d;
                const float val = acc[mt][nt][r] + bcol;
                if (sel == 2)
                    vout[off] = val;
                else
                    dstBF[off] = f2bf(val);
            }
        }
    }
}

// ---------------------------------------------------------------------------
// Scores + softmax, 32x32 MFMA version. Block = (head, 32-row block).
// 4 waves; wave w owns cols [256w, 256w+256) = 8 tiles of 32 cols.
// C/D layout: col = lane&31, row = (reg&3) + 8*(reg>>2) + 4*(lane>>5)
// -> every store instruction writes full 128B lines (32 lanes x 4B).
// ---------------------------------------------------------------------------
__global__ __launch_bounds__(256, 2)
void attn_kernel(const short* __restrict__ qws, const short* __restrict__ kws,
                 float* __restrict__ attnOut)
{
    const int rb = blockIdx.x;   // 0..31 (32-row block)
    const int bh = blockIdx.y;   // 0..63 (b*H + h)
    const int t  = threadIdx.x;
    const int w  = t >> 6;
    const int lane = t & 63;
    const int li = lane & 31;
    const int hi = lane >> 5;

    const short* Qb = qws + (size_t)bh * (Nc * Dc);
    const short* Kb = kws + (size_t)bh * (Nc * Dc);

    // Q fragments: lane holds Q[rb*32+li][s*16 + hi*8 + i]
    s16x8 qF[4];
    {
        const short* qp = Qb + (size_t)(rb * 32 + li) * Dc + hi * 8;
#pragma unroll
        for (int s = 0; s < 4; ++s)
            qF[s] = *(const s16x8*)(qp + s * 16);
    }

    f32x16 acc[8];
#pragma unroll
    for (int i = 0; i < 8; ++i) acc[i] = (f32x16)(0.f);

    const int colbase = w * 256;
#pragma unroll
    for (int ct = 0; ct < 8; ++ct) {
        const short* kp = Kb + (size_t)(colbase + ct * 32 + li) * Dc + hi * 8;
#pragma unroll
        for (int s = 0; s < 4; ++s) {
            s16x8 kf = *(const s16x8*)(kp + s * 16);
            acc[ct] = __builtin_amdgcn_mfma_f32_32x32x16_bf16(qF[s], kf, acc[ct], 0, 0, 0);
        }
    }

    // ---- row max (rows live in regs; 32-lane shfl reduce stays in-half) ----
    float mx[16];
#pragma unroll
    for (int r = 0; r < 16; ++r) {
        float m = acc[0][r];
#pragma unroll
        for (int ct = 1; ct < 8; ++ct) m = fmaxf(m, acc[ct][r]);
#pragma unroll
        for (int off = 1; off < 32; off <<= 1)
            m = fmaxf(m, __shfl_xor(m, off));
        mx[r] = m;
    }

    __shared__ float red[4][32];
    if (li == 0) {
#pragma unroll
        for (int r = 0; r < 16; ++r)
            red[w][(r & 3) + 8 * (r >> 2) + 4 * hi] = mx[r];
    }
    __syncthreads();
    const float c = 1.44269504f / 32.0f;   // log2(e) / SCALE, SCALE = 32
#pragma unroll
    for (int r = 0; r < 16; ++r) {
        const int row = (r & 3) + 8 * (r >> 2) + 4 * hi;
        float m = fmaxf(fmaxf(red[0][row], red[1][row]),
                        fmaxf(red[2][row], red[3][row]));
        mx[r] = -m * c;                    // reuse as exp2 bias
    }
    __syncthreads();

    // ---- exp + row sum: p = exp2(s*c + (-m*c)) ----
    float sm[16];
#pragma unroll
    for (int r = 0; r < 16; ++r) sm[r] = 0.f;
#pragma unroll
    for (int ct = 0; ct < 8; ++ct) {
#pragma unroll
        for (int r = 0; r < 16; ++r) {
            float p = __builtin_amdgcn_exp2f(fmaf(acc[ct][r], c, mx[r]));
            acc[ct][r] = p;
            sm[r] += p;
        }
    }
#pragma unroll
    for (int r = 0; r < 16; ++r) {
#pragma unroll
        for (int off = 1; off < 32; off <<= 1)
            sm[r] += __shfl_xor(sm[r], off);
    }
    if (li == 0) {
#pragma unroll
        for (int r = 0; r < 16; ++r)
            red[w][(r & 3) + 8 * (r >> 2) + 4 * hi] = sm[r];
    }
    __syncthreads();
#pragma unroll
    for (int r = 0; r < 16; ++r) {
        const int row = (r & 3) + 8 * (r >> 2) + 4 * hi;
        sm[r] = 1.0f / (red[0][row] + red[1][row] + red[2][row] + red[3][row]);
    }

    // ---- write normalized attn: full 128B-line segments ----
    float* outp = attnOut + (size_t)bh * (Nc * Nc) + (size_t)(rb * 32) * Nc;
#pragma unroll
    for (int ct = 0; ct < 8; ++ct) {
        const int col = colbase + ct * 32 + li;
#pragma unroll
        for (int r = 0; r < 16; ++r) {
            const int row = (r & 3) + 8 * (r >> 2) + 4 * hi;
            outp[(size_t)row * Nc + col] = acc[ct][r] * sm[r];
        }
    }
}

extern "C" void kernel_launch(void* const* d_in, const int* in_sizes, int n_in,
                              void* d_out, int out_size, void* d_ws, size_t ws_size,
                              hipStream_t stream) {
    const float* q  = (const float*)d_in[0];
    const float* k  = (const float*)d_in[1];
    const float* v  = (const float*)d_in[2];
    const float* Wq = (const float*)d_in[3];
    const float* bq = (const float*)d_in[4];
    const float* Wk = (const float*)d_in[5];
    const float* bk = (const float*)d_in[6];
    const float* Wv = (const float*)d_in[7];
    const float* bv = (const float*)d_in[8];

    float* out0 = (float*)d_out;                      // (B,H,N,D) fp32
    float* attn = (float*)d_out + OUT0_ELEMS;         // (B,H,N,N) fp32

    short* qws = (short*)d_ws;                        // bf16 Q [b][h][n][d]
    short* kws = qws + (size_t)Mc * Ec;               // bf16 K [b][h][n][d]

    proj_kernel<<<dim3(32, 8, 3), 256, 0, stream>>>(
        q, k, v, Wq, Wk, Wv, bq, bk, bv, qws, kws, out0);
    attn_kernel<<<dim3(32, 64), 256, 0, stream>>>(qws, kws, attn);
}